// Round 1
// baseline (24.572 us; speedup 1.0000x reference)
//
#include <hip/hip_runtime.h>
#include <math.h>

// Problem constants (from reference): B=16, D=128, T=512.
#define B_DIM 16
#define D_DIM 128
#define T_DIM 512

// ---------------------------------------------------------------------------
// Kernel 1: Ksum[b*D + j] = sum_t keys[b, j, t]
// One 64-lane wave per row; each lane loads two float4 (8 floats), shfl-reduce.
// Grid: (B*D)/4 blocks of 256 threads (4 waves/block).
// ---------------------------------------------------------------------------
__global__ __launch_bounds__(256) void ksum_kernel(const float* __restrict__ keys,
                                                   float* __restrict__ ksum) {
    int gwave = (blockIdx.x * 256 + threadIdx.x) >> 6;  // global wave id == row
    int lane = threadIdx.x & 63;
    const float4* row = reinterpret_cast<const float4*>(keys + (size_t)gwave * T_DIM);
    float4 a = row[lane];        // 512 floats = 128 float4; lanes cover 0..63
    float4 c = row[lane + 64];   // and 64..127
    float s = a.x + a.y + a.z + a.w + c.x + c.y + c.z + c.w;
    #pragma unroll
    for (int off = 32; off > 0; off >>= 1) s += __shfl_down(s, off, 64);
    if (lane == 0) ksum[gwave] = s;
}

// ---------------------------------------------------------------------------
// Kernel 2: per block = (b, tile of 8 consecutive i rows).
//   - load Ksum[b,:] into LDS
//   - per-wave qsum of the 8 query rows
//   - logits + softmax (wave w handles rows 2w, 2w+1; 128 j across 64 lanes)
//   - V: out[b,i,:] = sum_j w[i][j] * values[b,j,:], float4-vectorized over t
// Grid: B * (D/8) = 256 blocks of 256 threads.
// ---------------------------------------------------------------------------
__global__ __launch_bounds__(256) void attn_kernel(const float* __restrict__ queries,
                                                   const float* __restrict__ values,
                                                   const float* __restrict__ para,
                                                   const float* __restrict__ para2,
                                                   const float* __restrict__ ksum,
                                                   float* __restrict__ out) {
    const int IT = 8;                       // i-rows per block
    int b = blockIdx.x >> 4;                // D/IT = 16 tiles per batch
    int i0 = (blockIdx.x & 15) * IT;

    __shared__ float s_ksum[D_DIM];
    __shared__ float s_q[IT];
    __shared__ float s_w[IT][D_DIM];

    int tid = threadIdx.x;
    int lane = tid & 63;
    int wave = tid >> 6;

    if (tid < D_DIM) s_ksum[tid] = ksum[b * D_DIM + tid];

    // qsum: wave w reduces query rows 2w and 2w+1 of this tile
    #pragma unroll
    for (int rr = 0; rr < 2; ++rr) {
        int r = wave * 2 + rr;
        const float4* row =
            reinterpret_cast<const float4*>(queries + (size_t)(b * D_DIM + i0 + r) * T_DIM);
        float4 a = row[lane];
        float4 c = row[lane + 64];
        float s = a.x + a.y + a.z + a.w + c.x + c.y + c.z + c.w;
        #pragma unroll
        for (int off = 32; off > 0; off >>= 1) s += __shfl_down(s, off, 64);
        if (lane == 0) s_q[r] = s;
    }
    __syncthreads();

    // logit scale: para0 * T^-1  (mean of irfft keeps only DC/T)  * T^-0.5 (softmax scale)
    float cscale = para[0] / (512.0f * sqrtf(512.0f));

    // softmax rows: wave w handles rows 2w, 2w+1; lane covers j=lane and j=lane+64
    #pragma unroll
    for (int rr = 0; rr < 2; ++rr) {
        int r = wave * 2 + rr;
        float q = s_q[r];
        const float* p2row = para2 + (size_t)(i0 + r) * D_DIM;
        float l0 = cscale * q * s_ksum[lane] * p2row[lane];
        float l1 = cscale * q * s_ksum[lane + 64] * p2row[lane + 64];
        float m = fmaxf(l0, l1);
        #pragma unroll
        for (int off = 32; off > 0; off >>= 1) m = fmaxf(m, __shfl_xor(m, off, 64));
        float e0 = __expf(l0 - m);
        float e1 = __expf(l1 - m);
        float s = e0 + e1;
        #pragma unroll
        for (int off = 32; off > 0; off >>= 1) s += __shfl_xor(s, off, 64);
        float inv = 1.0f / s;
        s_w[r][lane] = e0 * inv;
        s_w[r][lane + 64] = e1 * inv;
    }
    __syncthreads();

    // V accumulation: thread -> (half, t4). half picks rows r0..r0+3, t4 is a
    // float4 column (128 float4 == 512 t). values loads coalesced across t4.
    int half = tid >> 7;       // 0 or 1
    int t4 = tid & 127;
    int r0 = half * 4;
    const float4* v4 = reinterpret_cast<const float4*>(values + (size_t)b * D_DIM * T_DIM);
    float4 acc[4] = {};
    for (int j = 0; j < D_DIM; ++j) {
        float4 v = v4[j * (T_DIM / 4) + t4];
        #pragma unroll
        for (int r = 0; r < 4; ++r) {
            float w = s_w[r0 + r][j];   // wave-uniform -> LDS broadcast
            acc[r].x += w * v.x;
            acc[r].y += w * v.y;
            acc[r].z += w * v.z;
            acc[r].w += w * v.w;
        }
    }
    float4* out4 = reinterpret_cast<float4*>(out + (size_t)(b * D_DIM + i0) * T_DIM);
    #pragma unroll
    for (int r = 0; r < 4; ++r) {
        out4[(r0 + r) * (T_DIM / 4) + t4] = acc[r];
    }
}

extern "C" void kernel_launch(void* const* d_in, const int* in_sizes, int n_in,
                              void* d_out, int out_size, void* d_ws, size_t ws_size,
                              hipStream_t stream) {
    const float* queries = (const float*)d_in[0];  // [B, D, T]
    const float* keys    = (const float*)d_in[1];  // [B, D, T]
    const float* values  = (const float*)d_in[2];  // [B, D, T]
    // d_in[3] = attn_mask (unused)
    const float* para    = (const float*)d_in[4];  // [25]
    const float* para2   = (const float*)d_in[5];  // [D, D]
    float* out = (float*)d_out;                    // [B, D, T] fp32
    float* ksum = (float*)d_ws;                    // B*D floats of scratch

    ksum_kernel<<<(B_DIM * D_DIM) / 4, 256, 0, stream>>>(keys, ksum);
    attn_kernel<<<B_DIM * (D_DIM / 8), 256, 0, stream>>>(queries, values, para, para2, ksum, out);
}

// Round 2
// 17.634 us; speedup vs baseline: 1.3935x; 1.3935x over previous
//
#include <hip/hip_runtime.h>
#include <math.h>

// Problem constants (from reference): B=16, D=128, T=512.
#define B_DIM 16
#define D_DIM 128
#define T_DIM 512

// ---------------------------------------------------------------------------
// Kernel 1: Ksum[b*D + j] = sum_t keys[b, j, t]
// One 64-lane wave per row; each lane loads two float4 (8 floats), shfl-reduce.
// ---------------------------------------------------------------------------
__global__ __launch_bounds__(256) void ksum_kernel(const float* __restrict__ keys,
                                                   float* __restrict__ ksum) {
    int gwave = (blockIdx.x * 256 + threadIdx.x) >> 6;  // global wave id == row
    int lane = threadIdx.x & 63;
    const float4* row = reinterpret_cast<const float4*>(keys + (size_t)gwave * T_DIM);
    float4 a = row[lane];
    float4 c = row[lane + 64];
    float s = a.x + a.y + a.z + a.w + c.x + c.y + c.z + c.w;
    #pragma unroll
    for (int off = 32; off > 0; off >>= 1) s += __shfl_down(s, off, 64);
    if (lane == 0) ksum[gwave] = s;
}

// ---------------------------------------------------------------------------
// Kernel 2: block = (b, 8-row i-tile), 512 threads (8 waves).
//   blockIdx = tile*16 + b  -> all tiles of batch b land on XCD b%8 (L2 reuse).
//   wave w: qsum + softmax of row w (weights stored transposed s_w[j][r]).
//   V phase: thread = (jq in 0..3, t4 in 0..127); each group covers 32 j's,
//   so values[b] is read exactly ONCE per block; partials combined via LDS.
// ---------------------------------------------------------------------------
__global__ __launch_bounds__(512) void attn_kernel(const float* __restrict__ queries,
                                                   const float* __restrict__ values,
                                                   const float* __restrict__ para,
                                                   const float* __restrict__ para2,
                                                   const float* __restrict__ ksum,
                                                   float* __restrict__ out) {
    int b = blockIdx.x & 15;
    int i0 = (blockIdx.x >> 4) * 8;

    __shared__ float s_ksum[D_DIM];
    __shared__ float s_q[8];
    __shared__ float s_w[D_DIM][8];          // transposed: [j][row]
    __shared__ float4 s_part[4][8][T_DIM / 4];  // 64 KB partial accumulators

    int tid = threadIdx.x;
    int lane = tid & 63;
    int wave = tid >> 6;

    if (tid < D_DIM) s_ksum[tid] = ksum[b * D_DIM + tid];

    // qsum: wave w reduces query row i0+w
    {
        const float4* qrow =
            reinterpret_cast<const float4*>(queries + (size_t)(b * D_DIM + i0 + wave) * T_DIM);
        float4 a = qrow[lane];
        float4 c = qrow[lane + 64];
        float s = a.x + a.y + a.z + a.w + c.x + c.y + c.z + c.w;
        #pragma unroll
        for (int off = 32; off > 0; off >>= 1) s += __shfl_down(s, off, 64);
        if (lane == 0) s_q[wave] = s;
    }
    __syncthreads();

    // logit = para0/(T*sqrt(T)) * qsum_i * ksum_j * para2[i,j]; softmax over j.
    float cscale = para[0] / (512.0f * sqrtf(512.0f));
    {
        int r = wave;                     // one row per wave
        float q = s_q[r];
        const float* p2row = para2 + (size_t)(i0 + r) * D_DIM;
        float l0 = cscale * q * s_ksum[lane] * p2row[lane];
        float l1 = cscale * q * s_ksum[lane + 64] * p2row[lane + 64];
        float m = fmaxf(l0, l1);
        #pragma unroll
        for (int off = 32; off > 0; off >>= 1) m = fmaxf(m, __shfl_xor(m, off, 64));
        float e0 = __expf(l0 - m);
        float e1 = __expf(l1 - m);
        float s = e0 + e1;
        #pragma unroll
        for (int off = 32; off > 0; off >>= 1) s += __shfl_xor(s, off, 64);
        float inv = 1.0f / s;
        s_w[lane][r] = e0 * inv;
        s_w[lane + 64][r] = e1 * inv;
    }
    __syncthreads();

    // V phase
    int jq = tid >> 7;        // 0..3: j-quarter
    int t4 = tid & 127;       // float4 column
    const float4* v4 = reinterpret_cast<const float4*>(values) + (size_t)b * D_DIM * (T_DIM / 4);
    float4 acc[8];
    #pragma unroll
    for (int r = 0; r < 8; ++r) acc[r] = make_float4(0.f, 0.f, 0.f, 0.f);

    #define FMA4(A, W) \
        A.x += (W) * v.x; A.y += (W) * v.y; A.z += (W) * v.z; A.w += (W) * v.w;

    int jbeg = jq * 32;
    #pragma unroll 8
    for (int j = jbeg; j < jbeg + 32; ++j) {
        float4 v = v4[j * (T_DIM / 4) + t4];
        const float4* wp = reinterpret_cast<const float4*>(&s_w[j][0]);
        float4 w0 = wp[0];
        float4 w1 = wp[1];
        FMA4(acc[0], w0.x) FMA4(acc[1], w0.y) FMA4(acc[2], w0.z) FMA4(acc[3], w0.w)
        FMA4(acc[4], w1.x) FMA4(acc[5], w1.y) FMA4(acc[6], w1.z) FMA4(acc[7], w1.w)
    }
    #undef FMA4

    #pragma unroll
    for (int r = 0; r < 8; ++r) s_part[jq][r][t4] = acc[r];
    __syncthreads();

    // combine 4 partials; 1024 float4 outputs, 2 per thread
    float4* out4 = reinterpret_cast<float4*>(out);
    #pragma unroll
    for (int k = 0; k < 2; ++k) {
        int idx = tid + k * 512;
        int r = idx >> 7;
        int tt = idx & 127;
        float4 p0 = s_part[0][r][tt];
        float4 p1 = s_part[1][r][tt];
        float4 p2 = s_part[2][r][tt];
        float4 p3 = s_part[3][r][tt];
        float4 sum;
        sum.x = (p0.x + p1.x) + (p2.x + p3.x);
        sum.y = (p0.y + p1.y) + (p2.y + p3.y);
        sum.z = (p0.z + p1.z) + (p2.z + p3.z);
        sum.w = (p0.w + p1.w) + (p2.w + p3.w);
        out4[(size_t)(b * D_DIM + i0 + r) * (T_DIM / 4) + tt] = sum;
    }
}

extern "C" void kernel_launch(void* const* d_in, const int* in_sizes, int n_in,
                              void* d_out, int out_size, void* d_ws, size_t ws_size,
                              hipStream_t stream) {
    const float* queries = (const float*)d_in[0];  // [B, D, T]
    const float* keys    = (const float*)d_in[1];  // [B, D, T]
    const float* values  = (const float*)d_in[2];  // [B, D, T]
    // d_in[3] = attn_mask (unused)
    const float* para    = (const float*)d_in[4];  // [25]
    const float* para2   = (const float*)d_in[5];  // [D, D]
    float* out = (float*)d_out;                    // [B, D, T] fp32
    float* ksum = (float*)d_ws;                    // B*D floats of scratch

    ksum_kernel<<<(B_DIM * D_DIM) / 4, 256, 0, stream>>>(keys, ksum);
    attn_kernel<<<B_DIM * (D_DIM / 8), 512, 0, stream>>>(queries, values, para, para2, ksum, out);
}

// Round 3
// 13.522 us; speedup vs baseline: 1.8173x; 1.3041x over previous
//
#include <hip/hip_runtime.h>
#include <math.h>

// Problem constants (from reference): B=16, D=128, T=512.
#define B_DIM 16
#define D_DIM 128
#define T_DIM 512
#define NT4   (T_DIM / 4)   // 128 float4 per row

// ---------------------------------------------------------------------------
// Single fused kernel. Block = (b, 8-row i-tile), 512 threads (8 waves).
// blockIdx = tile*16 + b  -> all 16 tiles of batch b on XCD b%8 (L2 reuse of
// keys[b] and values[b]).
//
// Phase A: ksum[j] = sum_t keys[b,j,t] for ALL 128 j (recomputed per block;
//          keys[b] is L2-resident). 4 rows/wave/iter: 16 lanes x 8 float4
//          per row (coalesced), 4-level shfl_xor reduce.
// Phase B: qsum of row i0+wave, in-register (xor butterfly broadcast).
// Phase C: softmax over j: logit = para0/(T*sqrt(T)) * qsum_i*ksum_j*para2_ij
//          (irfft(...).mean(-1) keeps only the DC bin / T). Weights stored
//          transposed s_w[j][r].
// Phase D: V matmul: thread=(jq 0..3, t4 0..127); each j-quarter accumulates
//          8 rows x float4; values[b] read exactly once per block; partials
//          combined through LDS.
// ---------------------------------------------------------------------------
__global__ __launch_bounds__(512) void fused_attn_kernel(
    const float* __restrict__ queries,
    const float* __restrict__ keys,
    const float* __restrict__ values,
    const float* __restrict__ para,
    const float* __restrict__ para2,
    float* __restrict__ out) {

    int b  = blockIdx.x & 15;
    int i0 = (blockIdx.x >> 4) * 8;

    __shared__ float s_ksum[D_DIM];
    __shared__ float s_w[D_DIM][8];            // transposed: [j][row]
    __shared__ float4 s_part[4][8][NT4];       // 64 KB partial accumulators

    int tid  = threadIdx.x;
    int lane = tid & 63;
    int wave = tid >> 6;

    // ---- Phase A: full ksum for batch b ----
    const float4* k4 = reinterpret_cast<const float4*>(keys) + (size_t)b * D_DIM * NT4;
    {
        int rr = lane >> 4;    // row within quad (0..3)
        int c  = lane & 15;    // column chunk (0..15)
        #pragma unroll
        for (int it = 0; it < 4; ++it) {
            int row = it * 32 + wave * 4 + rr;
            const float4* krow = k4 + (size_t)row * NT4;
            float s = 0.f;
            #pragma unroll
            for (int k = 0; k < 8; ++k) {
                float4 v = krow[c + k * 16];
                s += (v.x + v.y) + (v.z + v.w);
            }
            // reduce across the 16 c-lanes (xor masks stay within c bits)
            s += __shfl_xor(s, 1, 64);
            s += __shfl_xor(s, 2, 64);
            s += __shfl_xor(s, 4, 64);
            s += __shfl_xor(s, 8, 64);
            if (c == 0) s_ksum[row] = s;
        }
    }

    // ---- Phase B: qsum of row i0+wave (in-register broadcast) ----
    float q;
    {
        const float4* qrow = reinterpret_cast<const float4*>(queries)
                             + (size_t)(b * D_DIM + i0 + wave) * NT4;
        float4 a = qrow[lane];
        float4 d = qrow[lane + 64];
        float s = (a.x + a.y) + (a.z + a.w) + (d.x + d.y) + (d.z + d.w);
        #pragma unroll
        for (int off = 32; off > 0; off >>= 1) s += __shfl_xor(s, off, 64);
        q = s;
    }
    __syncthreads();   // s_ksum ready

    // ---- Phase C: softmax of row i0+wave ----
    {
        float qc = q * (para[0] / (512.0f * sqrtf(512.0f)));
        const float* p2row = para2 + (size_t)(i0 + wave) * D_DIM;
        float l0 = qc * s_ksum[lane] * p2row[lane];
        float l1 = qc * s_ksum[lane + 64] * p2row[lane + 64];
        float m = fmaxf(l0, l1);
        #pragma unroll
        for (int off = 32; off > 0; off >>= 1) m = fmaxf(m, __shfl_xor(m, off, 64));
        float e0 = __expf(l0 - m);
        float e1 = __expf(l1 - m);
        float s = e0 + e1;
        #pragma unroll
        for (int off = 32; off > 0; off >>= 1) s += __shfl_xor(s, off, 64);
        float inv = 1.0f / s;
        s_w[lane][wave] = e0 * inv;
        s_w[lane + 64][wave] = e1 * inv;
    }
    __syncthreads();   // s_w ready

    // ---- Phase D: V accumulation ----
    int jq = tid >> 7;        // j-quarter 0..3
    int t4 = tid & 127;       // float4 column
    const float4* v4 = reinterpret_cast<const float4*>(values) + (size_t)b * D_DIM * NT4;
    float4 acc[8];
    #pragma unroll
    for (int r = 0; r < 8; ++r) acc[r] = make_float4(0.f, 0.f, 0.f, 0.f);

    #define FMA4(A, W) \
        A.x += (W) * v.x; A.y += (W) * v.y; A.z += (W) * v.z; A.w += (W) * v.w;

    int jbeg = jq * 32;
    #pragma unroll 8
    for (int j = jbeg; j < jbeg + 32; ++j) {
        float4 v = v4[(size_t)j * NT4 + t4];
        const float4* wp = reinterpret_cast<const float4*>(&s_w[j][0]);
        float4 w0 = wp[0];
        float4 w1 = wp[1];
        FMA4(acc[0], w0.x) FMA4(acc[1], w0.y) FMA4(acc[2], w0.z) FMA4(acc[3], w0.w)
        FMA4(acc[4], w1.x) FMA4(acc[5], w1.y) FMA4(acc[6], w1.z) FMA4(acc[7], w1.w)
    }
    #undef FMA4

    #pragma unroll
    for (int r = 0; r < 8; ++r) s_part[jq][r][t4] = acc[r];
    __syncthreads();

    // combine 4 partials; 1024 float4 outputs, 2 per thread
    float4* out4 = reinterpret_cast<float4*>(out);
    #pragma unroll
    for (int k = 0; k < 2; ++k) {
        int idx = tid + k * 512;
        int r = idx >> 7;
        int tt = idx & 127;
        float4 p0 = s_part[0][r][tt];
        float4 p1 = s_part[1][r][tt];
        float4 p2 = s_part[2][r][tt];
        float4 p3 = s_part[3][r][tt];
        float4 sum;
        sum.x = (p0.x + p1.x) + (p2.x + p3.x);
        sum.y = (p0.y + p1.y) + (p2.y + p3.y);
        sum.z = (p0.z + p1.z) + (p2.z + p3.z);
        sum.w = (p0.w + p1.w) + (p2.w + p3.w);
        out4[(size_t)(b * D_DIM + i0 + r) * NT4 + tt] = sum;
    }
}

extern "C" void kernel_launch(void* const* d_in, const int* in_sizes, int n_in,
                              void* d_out, int out_size, void* d_ws, size_t ws_size,
                              hipStream_t stream) {
    const float* queries = (const float*)d_in[0];  // [B, D, T]
    const float* keys    = (const float*)d_in[1];  // [B, D, T]
    const float* values  = (const float*)d_in[2];  // [B, D, T]
    // d_in[3] = attn_mask (unused)
    const float* para    = (const float*)d_in[4];  // [25]
    const float* para2   = (const float*)d_in[5];  // [D, D]
    float* out = (float*)d_out;                    // [B, D, T] fp32

    fused_attn_kernel<<<B_DIM * (D_DIM / 8), 512, 0, stream>>>(
        queries, keys, values, para, para2, out);
}